// Round 2
// baseline (2391.390 us; speedup 1.0000x reference)
//
#include <hip/hip_runtime.h>
#include <hip/hip_bf16.h>

// Problem constants (reference: DIM=1024, 16 heads, hd=64, N=4096, B=1)
#define SEQ     4096
#define NHEADS  16
#define HDIM    64
#define DIMSZ   1024
#define ATT_SCALE 0.125f   // 64^-0.5

// ws layout (floats):
//   Qb [16][64][4096]   head-major, TRANSPOSED (d, n)  -> coalesced attn staging
//   Kb [16][64][4096]   transposed likewise
//   Vb [16][4096][64]   natural (n, d)
//   attn [4096][1024]   attention output, (n, h*64+d)
// total = 4 * 4194304 floats = 67.1 MB
static constexpr size_t QSZ = (size_t)NHEADS * SEQ * HDIM;      // 4194304
static constexpr size_t HSTRIDE = (size_t)SEQ * HDIM;           // 262144 per head

// ---------------------------------------------------------------------------
// C = A * B^T (+bias).  A[M,K] row-major, B[N,K] row-major.
// 128x128 tile, BK=16, 256 threads, 8x8 per thread as 2x2 blocks of 4x4
// (split halves => conflict-free ds_read_b128 in the inner loop).
// MODE 0: C[M,N] += bias
// MODE 1: QKV scatter: col = part*1024 + head*64 + d;
//         part 0/1 (Q,K) -> transposed [h][d][n]; part 2 (V) -> [h][n][d]
// ---------------------------------------------------------------------------
template <int MODE>
__global__ __launch_bounds__(256, 4)
void sgemm_abt(const float* __restrict__ A, const float* __restrict__ B,
               const float* __restrict__ bias, float* __restrict__ C,
               float* __restrict__ Qb, float* __restrict__ Kb,
               float* __restrict__ Vb, int M, int N, int K)
{
    __shared__ float As[16][128];
    __shared__ float Bs[16][128];
    const int t  = threadIdx.x;
    const int tx = t & 15;
    const int ty = t >> 4;
    const int m0 = blockIdx.y * 128;
    const int n0 = blockIdx.x * 128;

    float c[2][2][4][4] = {};

    const float* Ap = A + (size_t)m0 * K;
    const float* Bp = B + (size_t)n0 * K;

    for (int k0 = 0; k0 < K; k0 += 16) {
        // ---- stage 128x16 of A and B (K-transposed into LDS) ----
        #pragma unroll
        for (int rep = 0; rep < 2; ++rep) {
            const int idx = rep * 256 + t;
            const int r  = idx >> 2;
            const int kv = (idx & 3) << 2;
            float4 va = *(const float4*)(Ap + (size_t)r * K + k0 + kv);
            As[kv + 0][r] = va.x; As[kv + 1][r] = va.y;
            As[kv + 2][r] = va.z; As[kv + 3][r] = va.w;
            float4 vb = *(const float4*)(Bp + (size_t)r * K + k0 + kv);
            Bs[kv + 0][r] = vb.x; Bs[kv + 1][r] = vb.y;
            Bs[kv + 2][r] = vb.z; Bs[kv + 3][r] = vb.w;
        }
        __syncthreads();

        #pragma unroll
        for (int k = 0; k < 16; ++k) {
            const float4 a0 = *(const float4*)&As[k][ty << 2];
            const float4 a1 = *(const float4*)&As[k][64 + (ty << 2)];
            const float4 b0 = *(const float4*)&Bs[k][tx << 2];
            const float4 b1 = *(const float4*)&Bs[k][64 + (tx << 2)];
            const float av[2][4] = {{a0.x, a0.y, a0.z, a0.w},
                                    {a1.x, a1.y, a1.z, a1.w}};
            const float bv[2][4] = {{b0.x, b0.y, b0.z, b0.w},
                                    {b1.x, b1.y, b1.z, b1.w}};
            #pragma unroll
            for (int rh = 0; rh < 2; ++rh)
                #pragma unroll
                for (int ch = 0; ch < 2; ++ch)
                    #pragma unroll
                    for (int i = 0; i < 4; ++i)
                        #pragma unroll
                        for (int j = 0; j < 4; ++j)
                            c[rh][ch][i][j] = fmaf(av[rh][i], bv[ch][j],
                                                   c[rh][ch][i][j]);
        }
        __syncthreads();
    }

    // ---- epilogue ----
    if constexpr (MODE == 0) {
        #pragma unroll
        for (int ch = 0; ch < 2; ++ch) {
            const int col = n0 + ch * 64 + (tx << 2);
            const float4 b4 = *(const float4*)(bias + col);
            #pragma unroll
            for (int rh = 0; rh < 2; ++rh)
                #pragma unroll
                for (int i = 0; i < 4; ++i) {
                    const int row = m0 + rh * 64 + (ty << 2) + i;
                    float4 o;
                    o.x = c[rh][ch][i][0] + b4.x;
                    o.y = c[rh][ch][i][1] + b4.y;
                    o.z = c[rh][ch][i][2] + b4.z;
                    o.w = c[rh][ch][i][3] + b4.w;
                    *(float4*)(C + (size_t)row * N + col) = o;
                }
        }
    } else {
        #pragma unroll
        for (int ch = 0; ch < 2; ++ch) {
            const int col  = n0 + ch * 64 + (tx << 2);
            const int part = col >> 10;            // uniform per (block, ch)
            const int head = (col >> 6) & 15;
            const int d0   = col & 63;
            if (part == 2) {
                float* base = Vb + (size_t)head * HSTRIDE;
                #pragma unroll
                for (int rh = 0; rh < 2; ++rh)
                    #pragma unroll
                    for (int i = 0; i < 4; ++i) {
                        const int row = m0 + rh * 64 + (ty << 2) + i;
                        float4 o;
                        o.x = c[rh][ch][i][0]; o.y = c[rh][ch][i][1];
                        o.z = c[rh][ch][i][2]; o.w = c[rh][ch][i][3];
                        *(float4*)(base + (size_t)row * HDIM + d0) = o;
                    }
            } else {
                float* base = (part == 0 ? Qb : Kb) + (size_t)head * HSTRIDE;
                #pragma unroll
                for (int rh = 0; rh < 2; ++rh) {
                    const int rowb = m0 + rh * 64 + (ty << 2);
                    #pragma unroll
                    for (int j = 0; j < 4; ++j) {
                        float4 o;   // 4 consecutive n for fixed d
                        o.x = c[rh][ch][0][j]; o.y = c[rh][ch][1][j];
                        o.z = c[rh][ch][2][j]; o.w = c[rh][ch][3][j];
                        *(float4*)(base + (size_t)(d0 + j) * SEQ + rowb) = o;
                    }
                }
            }
        }
    }
}

// ---------------------------------------------------------------------------
// Flash attention, fp32. Br=Bc=64, 256 threads (16x16, 4x4 micro-tile).
// Q/K input transposed [h][d][n]; V natural [h][n][d].
// Output: attn[n][head*64 + d]  (n-major, DIM columns)
// ---------------------------------------------------------------------------
__global__ __launch_bounds__(256, 2)
void attn_kernel(const float* __restrict__ Qb, const float* __restrict__ Kb,
                 const float* __restrict__ Vb, float* __restrict__ Out)
{
    __shared__ float Qt[64][64];   // [d][q]
    __shared__ float Kt[64][64];   // [d][k]
    __shared__ float Vs[64][64];   // [k][d]
    __shared__ float Ps[64][64];   // [q][*], XOR-swizzled columns

    const int t  = threadIdx.x;
    const int tx = t & 15;
    const int ty = t >> 4;
    const int qb   = blockIdx.x;
    const int head = blockIdx.y;

    const float* Qh = Qb + (size_t)head * HSTRIDE;
    const float* Kh = Kb + (size_t)head * HSTRIDE;
    const float* Vh = Vb + (size_t)head * HSTRIDE;

    // stage Q tile (transposed source -> direct, coalesced, bank-clean)
    #pragma unroll
    for (int rep = 0; rep < 4; ++rep) {
        const int idx = rep * 256 + t;
        const int d  = idx >> 4;
        const int q4 = (idx & 15) << 2;
        *(float4*)&Qt[d][q4] =
            *(const float4*)(Qh + (size_t)d * SEQ + qb * 64 + q4);
    }

    float m_i[4], l_i[4], o[4][4];
    #pragma unroll
    for (int i = 0; i < 4; ++i) {
        m_i[i] = -1e30f; l_i[i] = 0.f;
        #pragma unroll
        for (int j = 0; j < 4; ++j) o[i][j] = 0.f;
    }

    for (int kb = 0; kb < SEQ / 64; ++kb) {
        // ---- stage K (transposed src) and V ----
        #pragma unroll
        for (int rep = 0; rep < 4; ++rep) {
            const int idx = rep * 256 + t;
            const int r  = idx >> 4;
            const int c4 = (idx & 15) << 2;
            *(float4*)&Kt[r][c4] =
                *(const float4*)(Kh + (size_t)r * SEQ + kb * 64 + c4);
            *(float4*)&Vs[r][c4] =
                *(const float4*)(Vh + (size_t)(kb * 64 + r) * HDIM + c4);
        }
        __syncthreads();

        // ---- S = Q K^T (4x4 per thread) ----
        float s[4][4] = {};
        #pragma unroll 8
        for (int d = 0; d < 64; ++d) {
            const float4 qa = *(const float4*)&Qt[d][ty << 2];
            const float4 ka = *(const float4*)&Kt[d][tx << 2];
            const float qv[4] = {qa.x, qa.y, qa.z, qa.w};
            const float kv[4] = {ka.x, ka.y, ka.z, ka.w};
            #pragma unroll
            for (int i = 0; i < 4; ++i)
                #pragma unroll
                for (int j = 0; j < 4; ++j)
                    s[i][j] = fmaf(qv[i], kv[j], s[i][j]);
        }

        // ---- online softmax update ----
        float alpha[4];
        #pragma unroll
        for (int i = 0; i < 4; ++i) {
            #pragma unroll
            for (int j = 0; j < 4; ++j) s[i][j] *= ATT_SCALE;
            float rm = fmaxf(fmaxf(s[i][0], s[i][1]), fmaxf(s[i][2], s[i][3]));
            rm = fmaxf(rm, __shfl_xor(rm, 1));
            rm = fmaxf(rm, __shfl_xor(rm, 2));
            rm = fmaxf(rm, __shfl_xor(rm, 4));
            rm = fmaxf(rm, __shfl_xor(rm, 8));
            const float mn = fmaxf(m_i[i], rm);
            alpha[i] = __expf(m_i[i] - mn);
            m_i[i] = mn;
            float rs = 0.f;
            #pragma unroll
            for (int j = 0; j < 4; ++j) {
                s[i][j] = __expf(s[i][j] - mn);
                rs += s[i][j];
            }
            rs += __shfl_xor(rs, 1);
            rs += __shfl_xor(rs, 2);
            rs += __shfl_xor(rs, 4);
            rs += __shfl_xor(rs, 8);
            l_i[i] = l_i[i] * alpha[i] + rs;
            #pragma unroll
            for (int j = 0; j < 4; ++j) o[i][j] *= alpha[i];
        }

        // ---- write P (swizzled) ----
        #pragma unroll
        for (int i = 0; i < 4; ++i) {
            const int qi = (ty << 2) + i;
            float4 p4;
            p4.x = s[i][0]; p4.y = s[i][1]; p4.z = s[i][2]; p4.w = s[i][3];
            *(float4*)&Ps[qi][(tx ^ (qi & 15)) << 2] = p4;
        }
        __syncthreads();

        // ---- O += P V ----
        #pragma unroll 4
        for (int kv4 = 0; kv4 < 16; ++kv4) {
            float p[4][4];
            #pragma unroll
            for (int i = 0; i < 4; ++i) {
                const int qi = (ty << 2) + i;
                const float4 pp =
                    *(const float4*)&Ps[qi][(kv4 ^ (qi & 15)) << 2];
                p[i][0] = pp.x; p[i][1] = pp.y; p[i][2] = pp.z; p[i][3] = pp.w;
            }
            #pragma unroll
            for (int kc = 0; kc < 4; ++kc) {
                const float4 vv = *(const float4*)&Vs[(kv4 << 2) + kc][tx << 2];
                const float vr[4] = {vv.x, vv.y, vv.z, vv.w};
                #pragma unroll
                for (int i = 0; i < 4; ++i)
                    #pragma unroll
                    for (int j = 0; j < 4; ++j)
                        o[i][j] = fmaf(p[i][kc], vr[j], o[i][j]);
            }
        }
        __syncthreads();   // protect Kt/Vs/Ps before next chunk's staging
    }

    // ---- finalize: divide by l, write [n][head*64+d] ----
    #pragma unroll
    for (int i = 0; i < 4; ++i) {
        const float inv = 1.0f / l_i[i];
        const int row = qb * 64 + (ty << 2) + i;
        float4 vout;
        vout.x = o[i][0] * inv; vout.y = o[i][1] * inv;
        vout.z = o[i][2] * inv; vout.w = o[i][3] * inv;
        *(float4*)(Out + (size_t)row * DIMSZ + head * HDIM + (tx << 2)) = vout;
    }
}

// ---------------------------------------------------------------------------
extern "C" void kernel_launch(void* const* d_in, const int* in_sizes, int n_in,
                              void* d_out, int out_size, void* d_ws,
                              size_t ws_size, hipStream_t stream)
{
    const float* x     = (const float*)d_in[0];   // [4096, 3072]
    const float* Wqkv  = (const float*)d_in[1];   // [3072, 3072]
    const float* Wproj = (const float*)d_in[2];   // [1024, 1024]
    const float* bproj = (const float*)d_in[3];   // [1024]
    float* ws   = (float*)d_ws;
    float* Qb   = ws;                 // [16][64][4096]
    float* Kb   = ws + QSZ;           // [16][64][4096]
    float* Vb   = ws + 2 * QSZ;       // [16][4096][64]
    float* attn = ws + 3 * QSZ;       // [4096][1024]
    float* out  = (float*)d_out;

    // 1) qkv = x @ Wqkv^T, scattered to Q/K (transposed) and V
    dim3 g1(3 * DIMSZ / 128, SEQ / 128);   // 24 x 32
    sgemm_abt<1><<<g1, 256, 0, stream>>>(x, Wqkv, nullptr, nullptr,
                                         Qb, Kb, Vb, SEQ, 3 * DIMSZ, 3 * DIMSZ);

    // 2) flash attention per (q-block, head)
    dim3 g2(SEQ / 64, NHEADS);             // 64 x 16
    attn_kernel<<<g2, 256, 0, stream>>>(Qb, Kb, Vb, attn);

    // 3) out = attn @ Wproj^T + bproj
    dim3 g3(DIMSZ / 128, SEQ / 128);       // 8 x 32
    sgemm_abt<0><<<g3, 256, 0, stream>>>(attn, Wproj, bproj, out,
                                         nullptr, nullptr, nullptr,
                                         SEQ, DIMSZ, DIMSZ);
}